// Round 1
// 448.207 us; speedup vs baseline: 1.0310x; 1.0310x over previous
//
#include <hip/hip_runtime.h>
#include <cfloat>
#include <cstddef>

#define B_ 32
#define C_ 8192
#define D_ 256
#define K_ 512
#define NCH 32
#define CPB (C_ / NCH) /* 256 c's per chunk */

typedef float f4n __attribute__((ext_vector_type(4)));  // native vec for nontemporal builtin

// ---------------- k1: column reduce over C (sum, min, 2nd-min) ----------------
// grid = B*NCH = 1024 blocks x 8 waves = exactly 8192 wave slots. acd streamed
// once, nontemporal (read-once, keep it out of L2).
__global__ __launch_bounds__(256) void k1_colreduce(const float* __restrict__ acd,
                                                    float* __restrict__ psum,
                                                    float* __restrict__ pm1,
                                                    float* __restrict__ pm2) {
    const int t = threadIdx.x;
    const int b = blockIdx.x / NCH, ch = blockIdx.x % NCH;
    const int d4 = t & 63;     // f4n column within D (64 x 4 floats = 256)
    const int coff = t >> 6;   // 4-way row split within the chunk

    const f4n* src = (const f4n*)(acd + ((size_t)b * C_ + (size_t)ch * CPB) * D_);

    f4n s  = (f4n){0.f, 0.f, 0.f, 0.f};
    f4n m1 = (f4n){FLT_MAX, FLT_MAX, FLT_MAX, FLT_MAX};
    f4n m2 = m1;

#define UPD3(f) { s.f += x.f; float mx = fmaxf(m1.f, x.f); m2.f = fminf(m2.f, mx); m1.f = fminf(m1.f, x.f); }
#pragma unroll 4
    for (int r = coff; r < CPB; r += 4) {
        f4n x = __builtin_nontemporal_load(&src[(size_t)r * 64 + d4]);
        UPD3(x) UPD3(y) UPD3(z) UPD3(w)
    }
#undef UPD3

    __shared__ f4n ls[256];
    __shared__ f4n l1[256];
    __shared__ f4n l2[256];
    ls[t] = s; l1[t] = m1; l2[t] = m2;
    __syncthreads();

    if (t < 64) {
        f4n S = ls[t], M1 = l1[t], M2 = l2[t];
#define CMB(f) { S.f += s2.f; float mx = fmaxf(M1.f, a1.f); M2.f = fminf(fminf(M2.f, a2.f), mx); M1.f = fminf(M1.f, a1.f); }
#pragma unroll
        for (int j = 64; j < 256; j += 64) {
            f4n s2 = ls[t + j], a1 = l1[t + j], a2 = l2[t + j];
            CMB(x) CMB(y) CMB(z) CMB(w)
        }
#undef CMB
        size_t o = ((size_t)b * NCH + ch) * 64 + t;
        ((f4n*)psum)[o] = S;
        ((f4n*)pm1)[o] = M1;
        ((f4n*)pm2)[o] = M2;
    }
}

// ------- k2: combine chunks -> dens/tot/overly in registers; fused det path ---
// One block per b (d = threadIdx). Per-(b,d) values never hit global memory:
// each block reduces its own contribution to one double. The det path (keys +
// radix-select-512 + total_det) runs inline behind a block-uniform LDS flag —
// it only executes when some d of THIS b has overly != 0.
__device__ __forceinline__ unsigned fmapk(float f) {
    unsigned u = __float_as_uint(f);
    return (u & 0x80000000u) ? ~u : (u | 0x80000000u);
}

__global__ __launch_bounds__(256) void k2_fused(const float* __restrict__ psum,
                                                const float* __restrict__ pm1,
                                                const float* __restrict__ pm2,
                                                const float* __restrict__ weight,
                                                const float* __restrict__ mu,
                                                const float* __restrict__ var,
                                                const int* __restrict__ labels,
                                                double* __restrict__ partial) {
    const int b = blockIdx.x, t = threadIdx.x;

    float sum = 0.f, m1 = FLT_MAX, m2 = FLT_MAX;
    for (int ch = 0; ch < NCH; ch++) {
        size_t o = ((size_t)b * NCH + ch) * D_ + t;
        float cs = psum[o], c1 = pm1[o], c2 = pm2[o];
        sum += cs;
        m2 = fminf(fminf(m2, c2), fmaxf(m1, c1));
        m1 = fminf(m1, c1);
    }
    const int lab = labels[b];
    const float sw = weight[(size_t)lab * D_ + t];
    const float muv = mu[b * D_ + t];
    const float v = var[b * D_ + t];
    const float diff = sw - muv;
    const float dens = expf(-(diff * diff) / (2.0f * v));
    const float tot = fmaxf(sum, 1e-8f);
    const float o_ = (m2 - m1 >= 0.2f * tot) ? 1.0f : 0.0f;

    // non-det term: dens/tot * (C - (C-1)*o)
    double contrib = (double)dens / (double)tot *
                     ((double)C_ - (double)(C_ - 1) * (double)o_);

    __shared__ unsigned anyo;
    if (t == 0) anyo = 0u;
    __syncthreads();
    if (o_ != 0.0f) atomicOr(&anyo, 1u);
    __syncthreads();

    if (anyo != 0u) {   // block-uniform -> __syncthreads inside is legal
        __shared__ unsigned kl[C_];      // 32 KiB mapped keys
        __shared__ float s_s[D_];
        __shared__ unsigned hist[256];
        __shared__ unsigned scan[256];
        __shared__ int sel[K_];
        __shared__ unsigned sh_pref, sh_want, sh_nsel;

        s_s[t] = sw;                     // sample weight row (d = t)
        if (t == 0) { sh_pref = 0u; sh_want = K_; sh_nsel = 0u; }
        __syncthreads();

        // keys: |w_c|^2 - 2 s.w_c
        for (int c = t; c < C_; c += 256) {
            const f4n* wr = (const f4n*)(weight + (size_t)c * D_);
            const f4n* sr = (const f4n*)s_s;
            float dot = 0.f, nsq = 0.f;
#pragma unroll 8
            for (int d4 = 0; d4 < D_ / 4; d4++) {
                f4n w = wr[d4], sv = sr[d4];
                dot += w.x * sv.x + w.y * sv.y + w.z * sv.z + w.w * sv.w;
                nsq += w.x * w.x + w.y * w.y + w.z * w.z + w.w * w.w;
            }
            kl[c] = fmapk(nsq - 2.0f * dot);
        }
        __syncthreads();

        // 4-pass radix select of the 512th-smallest mapped key
        for (int pass = 0; pass < 4; pass++) {
            const int shift = 24 - 8 * pass;
            hist[t] = 0u;
            __syncthreads();
            const unsigned pref = sh_pref;
            const unsigned pmask = (pass == 0) ? 0u : (0xFFFFFFFFu << (shift + 8));
            for (int c = t; c < C_; c += 256) {
                unsigned u = kl[c];
                if ((u & pmask) == (pref & pmask)) atomicAdd(&hist[(u >> shift) & 255u], 1u);
            }
            __syncthreads();
            unsigned h = hist[t];
            scan[t] = h;
            __syncthreads();
            for (int off = 1; off < 256; off <<= 1) {
                unsigned x = (t >= off) ? scan[t - off] : 0u;
                __syncthreads();
                scan[t] += x;
                __syncthreads();
            }
            const unsigned want = sh_want;
            const unsigned incl = scan[t], excl = incl - h;
            if (incl >= want && excl < want) {   // exactly one t satisfies this
                sh_pref = pref | ((unsigned)t << shift);
                sh_want = want - excl;
            }
            __syncthreads();
        }

        const unsigned Kk = sh_pref, quota = sh_want;
        for (int c = t; c < C_; c += 256) {
            unsigned u = kl[c];
            bool take = (u < Kk);
            if (!take && u == Kk) {
                unsigned r = 0;
                for (int j = 0; j < c; j++)
                    if (kl[j] == Kk) r++;
                take = (r < quota);   // lowest-index ties first (jax top_k order)
            }
            if (take) {
                unsigned s2 = atomicAdd(&sh_nsel, 1u);
                sel[s2] = c;
            }
        }
        __syncthreads();

        // total_det[d=t] = sum over 512 selected classes of exp densities
        const float nh = -0.5f / v;
        float acc = 0.f;
        for (int k = 0; k < K_; k++) {
            float w = weight[(size_t)sel[k] * D_ + t];   // lanes d coalesced
            float df = w - muv;
            acc += expf(df * df * nh);
        }
        double td = fmax((double)acc, 1e-8);
        contrib -= (double)dens / td * (double)(C_ - 1) * (double)o_;
    }

    // block reduce 256 doubles -> partial[b]
    __shared__ double red[256];
    red[t] = contrib;
    __syncthreads();
    for (int s2 = 128; s2 > 0; s2 >>= 1) {
        if (t < s2) red[t] += red[t + s2];
        __syncthreads();
    }
    if (t == 0) partial[b] = red[0];
}

// ---------------- k3: sum 32 per-b partials, scale, write scalar --------------
__global__ __launch_bounds__(64) void k3_final(const double* __restrict__ partial,
                                               float* __restrict__ out) {
    const int t = threadIdx.x;
    double v = (t < B_) ? partial[t] : 0.0;
#pragma unroll
    for (int off = 32; off > 0; off >>= 1) v += __shfl_down(v, off);
    if (t == 0) out[0] = (float)(v / ((double)B_ * (double)C_ * (double)D_));
}

extern "C" void kernel_launch(void* const* d_in, const int* in_sizes, int n_in,
                              void* d_out, int out_size, void* d_ws, size_t ws_size,
                              hipStream_t stream) {
    const float* weight = (const float*)d_in[0];
    const float* mu     = (const float*)d_in[1];
    const float* var    = (const float*)d_in[2];
    const float* acd    = (const float*)d_in[3];
    const int*   labels = (const int*)d_in[4];
    float* out = (float*)d_out;

    char* ws = (char*)d_ws;
    const size_t np = (size_t)B_ * NCH * D_;   // 262144 floats per partial array
    float* psum = (float*)ws;
    float* pm1  = psum + np;
    float* pm2  = pm1 + np;
    double* partial = (double*)(pm2 + np);     // 3*np*4 bytes is 8B-aligned

    k1_colreduce<<<B_ * NCH, 256, 0, stream>>>(acd, psum, pm1, pm2);
    k2_fused<<<B_, 256, 0, stream>>>(psum, pm1, pm2, weight, mu, var, labels, partial);
    k3_final<<<1, 64, 0, stream>>>(partial, out);
}